// Round 1
// 371.230 us; speedup vs baseline: 1.0562x; 1.0562x over previous
//
#include <hip/hip_runtime.h>
#include <hip/hip_bf16.h>
#include <math.h>

// Fused SpectralPooling: out = (A (x) A (x) A) * x per (b,c) volume,
// A[j][n] = sum_{k<28} D32[k][j] * D64[k][n]  (32x64).
// Phases V,U (64->32 contractions) on MFMA bf16; final n-contraction fp32 VALU.
//
// This revision:
//  - init_A kernel ELIMINATED: each block computes A in fp32 with exact integer
//    angle reduction ((2j+1)k mod 128 -> cosf arg <= 2pi, err ~1e-7 << bf16 noise).
//  - 1024 threads/block (16 waves/CU, was 8), 4 slabs/iter, 16 iters (was 32):
//    2x occupancy for latency hiding, half the barrier crossings.

typedef short short8 __attribute__((ext_vector_type(8)));
typedef float f32x4 __attribute__((ext_vector_type(4)));

__device__ inline unsigned pk_bf16(float a, float b) {
    union { __hip_bfloat162 h2; unsigned u; } c;
    c.h2 = __float22bfloat162_rn(make_float2(a, b));
    return c.u;
}

// grid = 256 blocks (one per (b,c) volume), 1024 threads (16 waves).
__global__ __launch_bounds__(1024, 4) void spectral_kernel(
    const float* __restrict__ x, float* __restrict__ out)
{
    // LDS (rows padded to 72 u16 / 36 f32 so b128 frag reads stay 16B-aligned,
    // low-way bank conflicts). Total 86.5 KB -> 1 block/CU, 16 waves/CU.
    __shared__ __align__(16) unsigned short Xbf[4][64][72]; // x slabs, bf16 (36.9 KB)
    __shared__ __align__(16) unsigned short Vbf[4][32][72]; // v[k][m], bf16 (18.4 KB)
    __shared__ __align__(16) float          Ubuf[4][32][36];// u[j][k], fp32 (18.4 KB)
    __shared__ __align__(16) unsigned short Abf[32][72];    // A bf16        ( 4.6 KB)
    __shared__ __align__(16) float          Atl[64][32];    // At fp32       ( 8.2 KB)

    const int t    = threadIdx.x;
    const int b    = blockIdx.x;
    const int lane = t & 63;
    const int l15  = lane & 15;
    const int q4   = lane >> 4;                              // quad 0..3
    const int w    = __builtin_amdgcn_readfirstlane(t >> 6); // wave 0..15
    const int sl   = w & 3;                                  // slab 0..3
    const int ws4  = w >> 2;                                 // 0..3
    const int m0   = ws4 * 16;                               // phase-V m-tile
    const int kt2  = ws4 & 1;                                // phase-U k-tile
    const int jt   = ws4 >> 1;                               // phase-U j-tile
    const int k32  = t & 31;
    const int j0   = t >> 5;                                 // 0..31

    const float* xb = x + (size_t)b * 262144;

    // prefetch slab quad 0 (overlaps A computation below)
    float4 r0, r1, r2, r3;
    {
        const float4* src = (const float4*)xb;
        r0 = src[t]; r1 = src[t + 1024]; r2 = src[t + 2048]; r3 = src[t + 3072];
    }

    // ---- compute A in-block (fp32, exact integer angle reduction) ----
    {
        const float PI64  = 0.04908738521234052f;   // pi/64
        const float PI128 = 0.02454369260617026f;   // pi/128
        const float S0    = 0.02209708691207961f;   // sqrt(1/32)*sqrt(1/64)
        for (int g = t; g < 2048; g += 1024) {
            int j = g >> 6;   // 0..31
            int n = g & 63;   // 0..63
            float a = S0;     // k = 0 term
            for (int k = 1; k < 28; ++k) {
                float cj = cosf((float)(((2 * j + 1) * k) & 127) * PI64);
                float cn = cosf((float)(((2 * n + 1) * k) & 255) * PI128);
                a = fmaf(2.0f * S0 * cj, cn, a);
            }
            __hip_bfloat16 h = __float2bfloat16(a);
            Abf[j][n] = *(unsigned short*)&h;   // A  [32][64] bf16
            Atl[n][j] = a;                      // At [64][32] fp32
        }
    }

    float acc[32];
#pragma unroll
    for (int i = 0; i < 32; ++i) acc[i] = 0.f;

    __syncthreads();  // A/At staged

    // constant B-fragments of A (shared by phases V and U), kept in VGPRs:
    // bv[r][c]: element j = A[r*16 + l15][c*32 + q4*8 + j]
    short8 bv00 = *(const short8*)&Abf[l15][q4 * 8];
    short8 bv01 = *(const short8*)&Abf[l15][32 + q4 * 8];
    short8 bv10 = *(const short8*)&Abf[16 + l15][q4 * 8];
    short8 bv11 = *(const short8*)&Abf[16 + l15][32 + q4 * 8];

    for (int it = 0; it < 16; ++it) {
        // ---- stage prefetched quad into LDS (fp32 -> bf16) ----
        {
            int q;
            q = t;
            *(uint2*)&Xbf[q >> 10][(q >> 4) & 63][(q & 15) * 4] =
                make_uint2(pk_bf16(r0.x, r0.y), pk_bf16(r0.z, r0.w));
            q = t + 1024;
            *(uint2*)&Xbf[q >> 10][(q >> 4) & 63][(q & 15) * 4] =
                make_uint2(pk_bf16(r1.x, r1.y), pk_bf16(r1.z, r1.w));
            q = t + 2048;
            *(uint2*)&Xbf[q >> 10][(q >> 4) & 63][(q & 15) * 4] =
                make_uint2(pk_bf16(r2.x, r2.y), pk_bf16(r2.z, r2.w));
            q = t + 3072;
            *(uint2*)&Xbf[q >> 10][(q >> 4) & 63][(q & 15) * 4] =
                make_uint2(pk_bf16(r3.x, r3.y), pk_bf16(r3.z, r3.w));
        }
        __syncthreads();  // b1

        // issue next prefetch (hidden behind compute)
        if (it < 15) {
            const float4* src = (const float4*)(xb + (size_t)(it + 1) * 16384);
            r0 = src[t]; r1 = src[t + 1024]; r2 = src[t + 2048]; r3 = src[t + 3072];
        }

        // ---- phase V (MFMA): v[m][k] = sum_p X[m][p] * A[k][p] ----
        // wave: slab sl, m-tile m0; both k-tiles; K-chunks p in [0,32),[32,64)
        {
            short8 xa0 = *(const short8*)&Xbf[sl][m0 + l15][q4 * 8];
            short8 xa1 = *(const short8*)&Xbf[sl][m0 + l15][32 + q4 * 8];
            f32x4 z = {0.f, 0.f, 0.f, 0.f};
            f32x4 v0 = __builtin_amdgcn_mfma_f32_16x16x32_bf16(xa0, bv00, z, 0, 0, 0);
            v0 = __builtin_amdgcn_mfma_f32_16x16x32_bf16(xa1, bv01, v0, 0, 0, 0);
            f32x4 v1 = __builtin_amdgcn_mfma_f32_16x16x32_bf16(xa0, bv10, z, 0, 0, 0);
            v1 = __builtin_amdgcn_mfma_f32_16x16x32_bf16(xa1, bv11, v1, 0, 0, 0);
            // D: row m = m0 + q4*4 + reg, col k = kt*16 + l15 -> Vbf[sl][k][m] bf16
            *(uint2*)&Vbf[sl][l15][m0 + q4 * 4] =
                make_uint2(pk_bf16(v0.x, v0.y), pk_bf16(v0.z, v0.w));
            *(uint2*)&Vbf[sl][16 + l15][m0 + q4 * 4] =
                make_uint2(pk_bf16(v1.x, v1.y), pk_bf16(v1.z, v1.w));
        }
        __syncthreads();  // b2

        // ---- phase U (MFMA): u[k][j] = sum_m v[k][m] * A[j][m] ----
        // wave: slab sl, k-tile kt2, j-tile jt; K-chunks m in [0,32),[32,64)
        {
            short8 va0 = *(const short8*)&Vbf[sl][kt2 * 16 + l15][q4 * 8];
            short8 va1 = *(const short8*)&Vbf[sl][kt2 * 16 + l15][32 + q4 * 8];
            f32x4 z = {0.f, 0.f, 0.f, 0.f};
            f32x4 u = __builtin_amdgcn_mfma_f32_16x16x32_bf16(
                va0, jt ? bv10 : bv00, z, 0, 0, 0);
            u = __builtin_amdgcn_mfma_f32_16x16x32_bf16(
                va1, jt ? bv11 : bv01, u, 0, 0, 0);
            // D: row k = kt2*16 + q4*4 + reg, col j = jt*16 + l15
            *(float4*)&Ubuf[sl][jt * 16 + l15][kt2 * 16 + q4 * 4] =
                make_float4(u.x, u.y, u.z, u.w);
        }
        __syncthreads();  // b3

        // ---- phase ACC (fp32 VALU): acc[i] += At[n][i] * u[j][k], 4 slabs ----
        {
            float u0 = Ubuf[0][j0][k32];
            float u1 = Ubuf[1][j0][k32];
            float u2 = Ubuf[2][j0][k32];
            float u3 = Ubuf[3][j0][k32];
            const float4* c0p = (const float4*)&Atl[4 * it + 0][0];  // uniform -> bcast
            const float4* c1p = (const float4*)&Atl[4 * it + 1][0];
            const float4* c2p = (const float4*)&Atl[4 * it + 2][0];
            const float4* c3p = (const float4*)&Atl[4 * it + 3][0];
#pragma unroll
            for (int i4 = 0; i4 < 8; ++i4) {
                float4 c0 = c0p[i4];
                float4 c1 = c1p[i4];
                float4 c2 = c2p[i4];
                float4 c3 = c3p[i4];
                acc[i4 * 4 + 0] += c0.x * u0 + c1.x * u1 + c2.x * u2 + c3.x * u3;
                acc[i4 * 4 + 1] += c0.y * u0 + c1.y * u1 + c2.y * u2 + c3.y * u3;
                acc[i4 * 4 + 2] += c0.z * u0 + c1.z * u1 + c2.z * u2 + c3.z * u3;
                acc[i4 * 4 + 3] += c0.w * u0 + c1.w * u1 + c2.w * u2 + c3.w * u3;
            }
        }
    }

    // ---- epilogue: out[b][i][j][k] ----
    float* ob = out + (size_t)b * 32768;
#pragma unroll
    for (int i = 0; i < 32; ++i)
        ob[i * 1024 + j0 * 32 + k32] = acc[i];
}

extern "C" void kernel_launch(void* const* d_in, const int* in_sizes, int n_in,
                              void* d_out, int out_size, void* d_ws, size_t ws_size,
                              hipStream_t stream) {
    const float* x = (const float*)d_in[0];
    float* out = (float*)d_out;
    (void)d_ws; (void)ws_size;

    spectral_kernel<<<256, 1024, 0, stream>>>(x, out);
}